// Round 11
// baseline (407.244 us; speedup 1.0000x reference)
//
#include <hip/hip_runtime.h>
#include <math.h>

// Problem constants
#define TC 256            // crop T
#define HC 128            // spatial H=W
#define Z2 512            // 2*T
#define Y2 256            // 2*H
#define X2 256            // 2*W
#define HW 16384          // HC*HC
#define LSTR256 260       // LDS line stride for 256-pt lines (float2)
#define LSTR512 519       // LDS line stride for 512-pt lines (float2)
#define WPAD 132          // row stride (float2) for A/B spectral arrays (1056B, non-pow2)
#define KZS 257           // stored z-spectral bins (Hermitian half along z)
#define MPAD 36           // LDS row stride (floats) for staged GEMM chunks (144B, 16B-aligned)

__device__ __forceinline__ float2 cadd(float2 a, float2 b){ return make_float2(a.x+b.x, a.y+b.y); }
__device__ __forceinline__ float2 csub(float2 a, float2 b){ return make_float2(a.x-b.x, a.y-b.y); }

// w stored as e^{-2*pi*i*j/N}. SGN=-1 uses w as-is (forward), SGN=+1 uses conj(w) (inverse).
template<int SGN>
__device__ __forceinline__ float2 cmul_tw(float2 z, float2 w){
  float wy = (SGN < 0) ? w.y : -w.y;
  return make_float2(z.x*w.x - z.y*wy, z.x*wy + z.y*w.x);
}
// SGN=-1: multiply by -i ; SGN=+1: multiply by +i
template<int SGN>
__device__ __forceinline__ float2 mul_pmi(float2 t){
  return (SGN < 0) ? make_float2(t.y, -t.x) : make_float2(-t.y, t.x);
}

// In-register 16-point DFT
template<int SGN>
__device__ __forceinline__ void dft16(float2 r[16], const float2* __restrict__ tw){
  float2 u[16];
  #pragma unroll
  for (int b2=0;b2<4;b2++){
    float2 x0=r[b2], x1=r[4+b2], x2=r[8+b2], x3=r[12+b2];
    float2 t0=cadd(x0,x2), t1=csub(x0,x2), t2=cadd(x1,x3), t3=csub(x1,x3);
    float2 y0=cadd(t0,t2), y2=csub(t0,t2);
    float2 t3i = mul_pmi<SGN>(t3);
    float2 y1=cadd(t1,t3i), y3=csub(t1,t3i);
    u[0*4+b2]=y0;
    u[1*4+b2]=cmul_tw<SGN>(y1, tw[(16*b2)&255]);
    u[2*4+b2]=cmul_tw<SGN>(y2, tw[(32*b2)&255]);
    u[3*4+b2]=cmul_tw<SGN>(y3, tw[(48*b2)&255]);
  }
  #pragma unroll
  for (int e2=0;e2<4;e2++){
    float2 x0=u[e2*4+0], x1=u[e2*4+1], x2=u[e2*4+2], x3=u[e2*4+3];
    float2 t0=cadd(x0,x2), t1=csub(x0,x2), t2=cadd(x1,x3), t3=csub(x1,x3);
    float2 t3i = mul_pmi<SGN>(t3);
    r[0*4+e2]=cadd(t0,t2);
    r[1*4+e2]=cadd(t1,t3i);
    r[2*4+e2]=csub(t0,t2);
    r[3*4+e2]=csub(t1,t3i);
  }
}

// 256-pt FFT on one LDS line (contiguous 256 float2 at ln), 16 threads/line, b = lane-in-line.
// Caller must __syncthreads() after filling ln.
template<int SGN>
__device__ __forceinline__ void fft256(float2* ln, int b, const float2* __restrict__ tw){
  float2 r[16];
  #pragma unroll
  for (int a=0;a<16;a++) r[a] = ln[16*a+b];
  dft16<SGN>(r, tw);
  #pragma unroll
  for (int e=1;e<16;e++) r[e] = cmul_tw<SGN>(r[e], tw[(b*e)&255]);
  __syncthreads();
  #pragma unroll
  for (int e=0;e<16;e++) ln[16*e+b] = r[e];
  __syncthreads();
  #pragma unroll
  for (int a=0;a<16;a++) r[a] = ln[16*b+a];
  dft16<SGN>(r, tw);
  __syncthreads();
  #pragma unroll
  for (int d=0;d<16;d++) ln[16*d+b] = r[d];
  __syncthreads();
}

// 512-pt FFT on one LDS line (contiguous 512 float2 at ln), 32 threads/line, lt in [0,32).
template<int SGN, bool CROP_OUT>
__device__ __forceinline__ void fft512(float2* ln, int lt,
        const float2* __restrict__ tw256, const float2* __restrict__ tw512){
  int team = lt >> 4, b = lt & 15;
  float2* sc = ln + team*256;
  float2 r[16];
  #pragma unroll
  for (int a=0;a<16;a++) r[a] = ln[2*(16*a+b) + team];
  dft16<SGN>(r, tw256);
  #pragma unroll
  for (int e=1;e<16;e++) r[e] = cmul_tw<SGN>(r[e], tw256[(b*e)&255]);
  __syncthreads();
  #pragma unroll
  for (int e=0;e<16;e++) sc[16*e+b] = r[e];
  __syncthreads();
  #pragma unroll
  for (int a=0;a<16;a++) r[a] = sc[16*b+a];
  dft16<SGN>(r, tw256);
  __syncthreads();
  if (team==0){
    #pragma unroll
    for (int d=0;d<16;d++) ln[16*d+b] = r[d];
  } else {
    #pragma unroll
    for (int d=0;d<16;d++){ int k=16*d+b; ln[256+k] = cmul_tw<SGN>(r[d], tw512[k]); }
  }
  __syncthreads();
  float2 res[8], res2[8];
  #pragma unroll
  for (int j=0;j<8;j++){
    int k = lt + 32*j;
    float2 E = ln[k], WO = ln[256+k];
    res[j]  = cadd(E,WO);
    res2[j] = csub(E,WO);
  }
  __syncthreads();
  #pragma unroll
  for (int j=0;j<8;j++){
    int k = lt + 32*j;
    ln[k] = res[j];
    if (!CROP_OUT) ln[256+k] = res2[j];
  }
  __syncthreads();
}

// ---------------- twiddle init ----------------
__global__ void k_init_tw(float2* tw256, float2* tw512){
  int j = threadIdx.x;  // 512 threads
  if (j < 512){
    double a = -6.283185307179586476925286766559 * (double)j / 512.0;
    tw512[j] = make_float2((float)cos(a), (float)sin(a));
  }
  if (j < 256){
    double a = -6.283185307179586476925286766559 * (double)j / 256.0;
    tw256[j] = make_float2((float)cos(a), (float)sin(a));
  }
}

// ---------------- Fused Pass 1: gemm1 (tmp = mtx @ fet*z^4) + fwd 512-pt z-FFT -> A -----------
// 16 hw per block, 512 threads. GEMM phase: mtx chunks staged in LDS (reusing the FFT buffer
// before the FFT fill -> LDS stays 66.4 KB, 2 blocks/CU); mtx (256 KB) is L2-resident across
// blocks. Each thread computes 8 tmp values (4 n x 2 hw) in registers, writes them into the
// FFT lines, then the standard 512-pt z-FFT runs.
__global__ __launch_bounds__(512) void k_zf_gemm(const float* __restrict__ mtxg,
      const float* __restrict__ fet, const float* __restrict__ gz,
      float2* __restrict__ A, const float2* __restrict__ tw256, const float2* __restrict__ tw512){
  __shared__ float2 buf[16*LSTR512];    // 66,432 B (union: GEMM staging, then FFT lines)
  float* S = (float*)buf;
  float* mtx_s = S;                      // [256][MPAD]
  float* d_s   = S + 256*MPAD;           // [16][MPAD]
  float* zz    = S + 256*MPAD + 16*MPAD; // [256]
  int tid = threadIdx.x;
  int hwbase = blockIdx.x*16;
  if (tid < 256){ float g = gz[tid]; float g2 = g*g; zz[tid] = g2*g2; }
  __syncthreads();
  int c2 = tid & 7, g8 = tid >> 3;       // GEMM mapping: 2 hw (2c2,2c2+1), 4 n (a*64+g8)
  float acc0[4] = {0.f,0.f,0.f,0.f};
  float acc1[4] = {0.f,0.f,0.f,0.f};
  for (int tc=0; tc<8; ++tc){
    #pragma unroll
    for (int e=0;e<16;e++){
      int idx = e*512 + tid;
      int n = idx >> 5, tl = idx & 31;
      mtx_s[n*MPAD + tl] = mtxg[n*256 + tc*32 + tl];
    }
    {
      int tl = tid >> 4, hwl = tid & 15;
      d_s[hwl*MPAD + tl] = fet[(size_t)(tc*32+tl)*HW + hwbase + hwl] * zz[tc*32+tl];
    }
    __syncthreads();
    float4 dr0[8], dr1[8];
    const float4* d0 = (const float4*)(d_s + (2*c2)*MPAD);
    const float4* d1 = (const float4*)(d_s + (2*c2+1)*MPAD);
    #pragma unroll
    for (int q=0;q<8;q++){ dr0[q]=d0[q]; dr1[q]=d1[q]; }
    #pragma unroll
    for (int a=0;a<4;a++){
      const float4* mrow = (const float4*)(mtx_s + (a*64+g8)*MPAD);
      float s0=0.f, s1=0.f;
      #pragma unroll
      for (int q=0;q<8;q++){
        float4 m = mrow[q];
        s0 += m.x*dr0[q].x + m.y*dr0[q].y + m.z*dr0[q].z + m.w*dr0[q].w;
        s1 += m.x*dr1[q].x + m.y*dr1[q].y + m.z*dr1[q].z + m.w*dr1[q].w;
      }
      acc0[a]+=s0; acc1[a]+=s1;
    }
    __syncthreads();
  }
  // fill FFT lines from registers (overwrites staging)
  #pragma unroll
  for (int a=0;a<4;a++){
    int n = a*64 + g8;
    buf[(2*c2)*LSTR512 + n]         = make_float2(acc0[a], 0.f);
    buf[(2*c2+1)*LSTR512 + n]       = make_float2(acc1[a], 0.f);
    buf[(2*c2)*LSTR512 + 256 + n]   = make_float2(0.f,0.f);
    buf[(2*c2+1)*LSTR512 + 256 + n] = make_float2(0.f,0.f);
  }
  __syncthreads();
  int hwl = tid & 15, ng = tid >> 4;
  int hw = hwbase + hwl;
  size_t colbase = (size_t)(hw>>7)*WPAD + (hw & 127);
  float2* ln = buf + hwl*LSTR512;
  fft512<-1,false>(ln, ng, tw256, tw512);
  #pragma unroll
  for (int a=0;a<8;a++){
    int n = a*32 + ng;
    A[(size_t)n*(128*WPAD) + colbase] = ln[n];
  }
  if (ng==0) A[(size_t)256*(128*WPAD) + colbase] = ln[256];
}

// ---------------- Pass 2: fwd y-FFT (128 -> 256) : A[kz][h][wx] -> B[kz][ky][wx] --------------
__global__ __launch_bounds__(256) void k_fft_yf(const float2* __restrict__ A,
      float2* __restrict__ B, const float2* __restrict__ tw256){
  __shared__ float2 buf[16*LSTR256];
  int tid = threadIdx.x;
  int w = tid & 15, b = tid >> 4;
  int kz = blockIdx.x;                 // 0..256
  int wx = blockIdx.y*16 + w;          // 0..127
  float2* ln = buf + w*LSTR256;
  size_t abase = (size_t)kz*(128*WPAD) + wx;
  #pragma unroll
  for (int a=0;a<8;a++){
    int n = 16*a + b;   // h 0..127
    ln[n] = A[abase + (size_t)n*WPAD];
    ln[n+128] = make_float2(0.f,0.f);
  }
  __syncthreads();
  fft256<-1>(ln, b, tw256);
  size_t bbase = (size_t)kz*(256*WPAD) + wx;
  #pragma unroll
  for (int a=0;a<16;a++){
    int n = 16*a + b;
    B[bbase + (size_t)n*WPAD] = ln[n];
  }
}

// ---------------- Pass 3: fused x-FFT (zero-pad 128->256) + filter + inv x-FFT, keep x<128 ----
__global__ __launch_bounds__(256) void k_x_filt(float2* __restrict__ B,
      const float* __restrict__ R, const float* __restrict__ I,
      const float* __restrict__ w0, const float* __restrict__ w1,
      const float2* __restrict__ tw256){
  __shared__ float2 buf[16*LSTR256];
  const float sc = 1.f/33554432.f;     // 1/(512*256*256)
  int tid = threadIdx.x;
  int wl = tid >> 4, b = tid & 15;
  int kz = blockIdx.y;                 // 0..256
  int ky = blockIdx.x*16 + wl;         // 0..255
  float2* ln = buf + wl*LSTR256;
  size_t rb = ((size_t)kz*256 + ky)*WPAD;
  #pragma unroll
  for (int a=0;a<8;a++){
    int n = 16*a + b;
    ln[n] = B[rb + n];
    ln[n+128] = make_float2(0.f,0.f);
  }
  __syncthreads();
  fft256<-1>(ln, b, tw256);
  unsigned mz = (512u - (unsigned)kz) & 511u;
  unsigned my = (256u - (unsigned)ky) & 255u;
  size_t trow = ((size_t)kz<<16) + (size_t)ky*256;
  size_t mrow = ((size_t)mz<<16) + (size_t)my*256;
  const float* Rrow  = R  + trow;
  const float* Irow  = I  + trow;
  const float* w0row = w0 + trow;
  const float* w1row = w1 + trow;
  const float* w0mr  = w0 + mrow;
  const float* w1mr  = w1 + mrow;
  #pragma unroll
  for (int L=0; L<4; ++L){
    int k0 = L*64 + 4*b;
    float4 Rf  = *(const float4*)(Rrow  + k0);
    float4 If  = *(const float4*)(Irow  + k0);
    float4 w0f = *(const float4*)(w0row + k0);
    float4 w1f = *(const float4*)(w1row + k0);
    float4 q0 = *(const float4*)(w0mr + 252 - k0);   // mx = 252-k0 .. 255-k0
    float4 q1 = *(const float4*)(w1mr + 252 - k0);
    float s0 = w0mr[(256 - k0) & 255];               // mx for j=0 (handles wrap kx=0)
    float s1 = w1mr[(256 - k0) & 255];
    float w0m0=s0, w0m1=q0.w, w0m2=q0.z, w0m3=q0.y;
    float w1m0=s1, w1m1=q1.w, w1m2=q1.z, w1m3=q1.y;
    float wr0=(Rf.x+0.5f*(w0f.x+w0m0))*sc, wi0=(If.x+0.5f*(w1f.x-w1m0))*sc;
    float wr1=(Rf.y+0.5f*(w0f.y+w0m1))*sc, wi1=(If.y+0.5f*(w1f.y-w1m1))*sc;
    float wr2=(Rf.z+0.5f*(w0f.z+w0m2))*sc, wi2=(If.z+0.5f*(w1f.z-w1m2))*sc;
    float wr3=(Rf.w+0.5f*(w0f.w+w0m3))*sc, wi3=(If.w+0.5f*(w1f.w-w1m3))*sc;
    float2 v0=ln[k0], v1=ln[k0+1], v2=ln[k0+2], v3=ln[k0+3];
    ln[k0]   = make_float2(v0.x*wr0 - v0.y*wi0, v0.x*wi0 + v0.y*wr0);
    ln[k0+1] = make_float2(v1.x*wr1 - v1.y*wi1, v1.x*wi1 + v1.y*wr1);
    ln[k0+2] = make_float2(v2.x*wr2 - v2.y*wi2, v2.x*wi2 + v2.y*wr2);
    ln[k0+3] = make_float2(v3.x*wr3 - v3.y*wi3, v3.x*wi3 + v3.y*wr3);
  }
  __syncthreads();   // ownership changed (64L+4b+j), must sync before inverse FFT reads 16a+b
  fft256<1>(ln, b, tw256);
  #pragma unroll
  for (int a=0;a<8;a++){
    int n = 16*a + b;    // x 0..127
    B[rb + n] = ln[n];
  }
}

// ---------------- Pass 4: inv y-FFT, keep y<128 : B[kz][ky][wx] -> A[kz][h][wx] ---------------
__global__ __launch_bounds__(256) void k_fft_yi(const float2* __restrict__ B,
      float2* __restrict__ A, const float2* __restrict__ tw256){
  __shared__ float2 buf[16*LSTR256];
  int tid = threadIdx.x;
  int w = tid & 15, b = tid >> 4;
  int kz = blockIdx.x;                 // 0..256
  int wx = blockIdx.y*16 + w;          // 0..127
  float2* ln = buf + w*LSTR256;
  size_t bbase = (size_t)kz*(256*WPAD) + wx;
  #pragma unroll
  for (int a=0;a<16;a++){
    int n = 16*a + b;
    ln[n] = B[bbase + (size_t)n*WPAD];
  }
  __syncthreads();
  fft256<1>(ln, b, tw256);
  size_t abase = (size_t)kz*(128*WPAD) + wx;
  #pragma unroll
  for (int a=0;a<8;a++){
    int n = 16*a + b;    // h 0..127
    A[abase + (size_t)n*WPAD] = ln[n];
  }
}

// ---------------- Fused Pass 5: inv 512-pt z-FFT (Hermitian) + gemm2 (out = mtxi @ vol) -------
// 16 hw per block, 512 threads. After the inverse FFT, vol[t] for the block's 16 columns sits
// in the LDS lines; the GEMM phase stages mtxi chunks in a separate LDS array (total ~103 KB,
// 1 block/CU) and writes out directly. Kills the vol buffer round-trip.
__global__ __launch_bounds__(512) void k_zi_gemm(const float2* __restrict__ A,
      const float* __restrict__ mtxig, float* __restrict__ out,
      const float2* __restrict__ tw256, const float2* __restrict__ tw512){
  __shared__ float2 buf[16*LSTR512];    // 66,432 B
  __shared__ float mtxi_s[256*MPAD];    // 36,864 B
  int tid = threadIdx.x;
  int hwbase = blockIdx.x*16;
  int hwl = tid & 15, ng = tid >> 4;
  int hw = hwbase + hwl;
  size_t colbase = (size_t)(hw>>7)*WPAD + (hw & 127);
  float2* ln = buf + hwl*LSTR512;
  #pragma unroll
  for (int a=0;a<8;a++){
    int n = a*32 + ng;
    ln[n] = A[(size_t)n*(128*WPAD) + colbase];
  }
  if (ng==0) ln[256] = A[(size_t)256*(128*WPAD) + colbase];
  __syncthreads();
  #pragma unroll
  for (int a=8;a<16;a++){
    int n = a*32 + ng;   // 256..511
    if (n > 256){ float2 v = ln[512-n]; ln[n] = make_float2(v.x, -v.y); }
  }
  __syncthreads();
  fft512<1,true>(ln, ng, tw256, tw512);
  // GEMM phase: out[m][hw] = sum_t mtxi[m][t] * vol[t][hw], vol = ln[t].x
  int c2 = tid & 7, g8 = tid >> 3;
  const float2* v0 = buf + (2*c2)*LSTR512;
  const float2* v1 = buf + (2*c2+1)*LSTR512;
  float acc0[4] = {0.f,0.f,0.f,0.f};
  float acc1[4] = {0.f,0.f,0.f,0.f};
  for (int tc=0; tc<8; ++tc){
    #pragma unroll
    for (int e=0;e<16;e++){
      int idx = e*512 + tid;
      int m = idx >> 5, tl = idx & 31;
      mtxi_s[m*MPAD + tl] = mtxig[m*256 + tc*32 + tl];
    }
    __syncthreads();
    #pragma unroll
    for (int q=0;q<8;q++){
      int t0 = tc*32 + 4*q;
      float2 a0=v0[t0], b0=v0[t0+1], c0=v0[t0+2], d0=v0[t0+3];
      float2 a1=v1[t0], b1=v1[t0+1], c1=v1[t0+2], d1=v1[t0+3];
      #pragma unroll
      for (int a=0;a<4;a++){
        float4 m4 = *(const float4*)(mtxi_s + (a*64+g8)*MPAD + 4*q);
        acc0[a] += m4.x*a0.x + m4.y*b0.x + m4.z*c0.x + m4.w*d0.x;
        acc1[a] += m4.x*a1.x + m4.y*b1.x + m4.z*c1.x + m4.w*d1.x;
      }
    }
    __syncthreads();
  }
  #pragma unroll
  for (int a=0;a<4;a++){
    int m = a*64 + g8;
    *(float2*)(out + (size_t)m*HW + hwbase + 2*c2) = make_float2(acc0[a], acc1[a]);
  }
}

extern "C" void kernel_launch(void* const* d_in, const int* in_sizes, int n_in,
                              void* d_out, int out_size, void* d_ws, size_t ws_size,
                              hipStream_t stream) {
  const float* fet = (const float*)d_in[0];           // (1,1,256,128,128)
  const float* gz  = (const float*)d_in[1];           // (1,256,1,1)
  const float* mtx = (const float*)d_in[2];           // (256,256)
  const float* mtxi= (const float*)d_in[3];           // (256,256)
  const float* Rr  = (const float*)d_in[4];           // (512,256,256)
  const float* Ii  = (const float*)d_in[5];           // (512,256,256)
  const float* lw  = (const float*)d_in[6];           // (2,512,256,256)
  const float* w0  = lw;
  const float* w1  = lw + (size_t)Z2*Y2*X2;
  float* out = (float*)d_out;

  char* ws = (char*)d_ws;
  const size_t OFF_TW256 = 0;
  const size_t OFF_TW512 = 2048;
  const size_t OFF_A     = 8192;
  const size_t A_BYTES   = (size_t)KZS*128*WPAD*sizeof(float2);       // 34.7 MB
  const size_t OFF_B     = OFF_A + A_BYTES;
  const size_t B_BYTES   = (size_t)KZS*256*WPAD*sizeof(float2);       // 69.5 MB
  const size_t NEED      = OFF_B + B_BYTES;                           // ~104 MB
  if (ws_size < NEED) return;   // diagnostic: leaves d_out zero

  float2* tw256 = (float2*)(ws + OFF_TW256);
  float2* tw512 = (float2*)(ws + OFF_TW512);
  float2* A     = (float2*)(ws + OFF_A);
  float2* B     = (float2*)(ws + OFF_B);

  hipLaunchKernelGGL(k_init_tw, dim3(1), dim3(512), 0, stream, tw256, tw512);
  hipLaunchKernelGGL(k_zf_gemm, dim3(1024), dim3(512), 0, stream, mtx, fet, gz, A, tw256, tw512);
  hipLaunchKernelGGL(k_fft_yf, dim3(KZS,8), dim3(256), 0, stream, A, B, tw256);
  hipLaunchKernelGGL(k_x_filt, dim3(16,KZS), dim3(256), 0, stream, B, Rr, Ii, w0, w1, tw256);
  hipLaunchKernelGGL(k_fft_yi, dim3(KZS,8), dim3(256), 0, stream, B, A, tw256);
  hipLaunchKernelGGL(k_zi_gemm, dim3(1024), dim3(512), 0, stream, A, mtxi, out, tw256, tw512);
}

// Round 12
// 338.067 us; speedup vs baseline: 1.2046x; 1.2046x over previous
//
#include <hip/hip_runtime.h>
#include <math.h>

// Problem constants
#define TC 256            // crop T
#define HC 128            // spatial H=W
#define Z2 512            // 2*T
#define Y2 256            // 2*H
#define X2 256            // 2*W
#define HW 16384          // HC*HC
#define LSTR256 260       // LDS line stride for 256-pt lines (float2)
#define LSTR512 519       // LDS line stride for 512-pt lines (float2)
#define MTSH 4
#define MT (1<<MTSH)      // per-thread m-tile in GEMM (16)
#define WPAD 132          // row stride (float2) for A/B spectral arrays (1056B, non-pow2)
#define KZS 257           // stored z-spectral bins (Hermitian half along z)

__device__ __forceinline__ float2 cadd(float2 a, float2 b){ return make_float2(a.x+b.x, a.y+b.y); }
__device__ __forceinline__ float2 csub(float2 a, float2 b){ return make_float2(a.x-b.x, a.y-b.y); }

// w stored as e^{-2*pi*i*j/N}. SGN=-1 uses w as-is (forward), SGN=+1 uses conj(w) (inverse).
template<int SGN>
__device__ __forceinline__ float2 cmul_tw(float2 z, float2 w){
  float wy = (SGN < 0) ? w.y : -w.y;
  return make_float2(z.x*w.x - z.y*wy, z.x*wy + z.y*w.x);
}
// SGN=-1: multiply by -i ; SGN=+1: multiply by +i
template<int SGN>
__device__ __forceinline__ float2 mul_pmi(float2 t){
  return (SGN < 0) ? make_float2(t.y, -t.x) : make_float2(-t.y, t.x);
}

// In-register 16-point DFT
template<int SGN>
__device__ __forceinline__ void dft16(float2 r[16], const float2* __restrict__ tw){
  float2 u[16];
  #pragma unroll
  for (int b2=0;b2<4;b2++){
    float2 x0=r[b2], x1=r[4+b2], x2=r[8+b2], x3=r[12+b2];
    float2 t0=cadd(x0,x2), t1=csub(x0,x2), t2=cadd(x1,x3), t3=csub(x1,x3);
    float2 y0=cadd(t0,t2), y2=csub(t0,t2);
    float2 t3i = mul_pmi<SGN>(t3);
    float2 y1=cadd(t1,t3i), y3=csub(t1,t3i);
    u[0*4+b2]=y0;
    u[1*4+b2]=cmul_tw<SGN>(y1, tw[(16*b2)&255]);
    u[2*4+b2]=cmul_tw<SGN>(y2, tw[(32*b2)&255]);
    u[3*4+b2]=cmul_tw<SGN>(y3, tw[(48*b2)&255]);
  }
  #pragma unroll
  for (int e2=0;e2<4;e2++){
    float2 x0=u[e2*4+0], x1=u[e2*4+1], x2=u[e2*4+2], x3=u[e2*4+3];
    float2 t0=cadd(x0,x2), t1=csub(x0,x2), t2=cadd(x1,x3), t3=csub(x1,x3);
    float2 t3i = mul_pmi<SGN>(t3);
    r[0*4+e2]=cadd(t0,t2);
    r[1*4+e2]=cadd(t1,t3i);
    r[2*4+e2]=csub(t0,t2);
    r[3*4+e2]=csub(t1,t3i);
  }
}

// Register-I/O 256-pt FFT: input r[a] = element 16a+b, output r[d] = element 16d+b.
// Uses ln (>=256 float2) as transpose scratch. ONE internal sync.
// Caller contract: ln must be safe to overwrite on entry (fresh, or sync'd);
// on return ln holds intermediates (sync before reusing it).
template<int SGN>
__device__ __forceinline__ void fft256_reg(float2 r[16], float2* ln, int b,
                                           const float2* __restrict__ tw){
  dft16<SGN>(r, tw);
  #pragma unroll
  for (int e=1;e<16;e++) r[e] = cmul_tw<SGN>(r[e], tw[(b*e)&255]);
  #pragma unroll
  for (int e=0;e<16;e++) ln[16*e+b] = r[e];
  __syncthreads();
  #pragma unroll
  for (int a=0;a<16;a++) r[a] = ln[16*b+a];
  dft16<SGN>(r, tw);
}

// Register-output 512-pt FFT on an LDS line of 512 float2. 32 threads/line, lt in [0,32).
// Input: ln[0..511] filled (if HALF_IN, only ln[0..255] need be valid; upper half treated 0).
// Output: res[j] = X[lt+32*j] (k=0..255); x256 = X[256] valid on lt==0 threads.
// Caller must __syncthreads() after filling ln. No trailing sync (ln dirty on return).
template<int SGN, bool HALF_IN>
__device__ __forceinline__ void fft512_reg(float2* ln, int lt,
        const float2* __restrict__ tw256, const float2* __restrict__ tw512,
        float2 res[8], float2& x256){
  int team = lt >> 4, b = lt & 15;
  float2* sc = ln + team*256;
  float2 r[16];
  #pragma unroll
  for (int a=0;a<16;a++){
    if (HALF_IN && a>=8) r[a] = make_float2(0.f,0.f);
    else r[a] = ln[2*(16*a+b) + team];
  }
  dft16<SGN>(r, tw256);
  #pragma unroll
  for (int e=1;e<16;e++) r[e] = cmul_tw<SGN>(r[e], tw256[(b*e)&255]);
  __syncthreads();
  #pragma unroll
  for (int e=0;e<16;e++) sc[16*e+b] = r[e];
  __syncthreads();
  #pragma unroll
  for (int a=0;a<16;a++) r[a] = sc[16*b+a];
  dft16<SGN>(r, tw256);
  __syncthreads();
  if (team==0){
    #pragma unroll
    for (int d=0;d<16;d++) ln[16*d+b] = r[d];
  } else {
    #pragma unroll
    for (int d=0;d<16;d++){ int k=16*d+b; ln[256+k] = cmul_tw<SGN>(r[d], tw512[k]); }
  }
  __syncthreads();
  #pragma unroll
  for (int j=0;j<8;j++){
    int k = lt + 32*j;
    float2 E = ln[k], WO = ln[256+k];
    res[j] = cadd(E,WO);
    if (j==0) x256 = csub(E,WO);
  }
}

// ---------------- twiddle init ----------------
__global__ void k_init_tw(float2* tw256, float2* tw512){
  int j = threadIdx.x;  // 512 threads
  if (j < 512){
    double a = -6.283185307179586476925286766559 * (double)j / 512.0;
    tw512[j] = make_float2((float)cos(a), (float)sin(a));
  }
  if (j < 256){
    double a = -6.283185307179586476925286766559 * (double)j / 256.0;
    tw256[j] = make_float2((float)cos(a), (float)sin(a));
  }
}

// ---------------- GEMM: C[m][hw] = sum_t A[m][t]*(gz?gz[t]^4:1) * B[t][hw] ----------------
__global__ __launch_bounds__(256) void k_gemm(const float* __restrict__ A,
    const float* __restrict__ Bv, const float* __restrict__ gz, float* __restrict__ C){
  __shared__ float As[64][MT];   // [tt][mi], scaled by zz[t]
  __shared__ float zz[256];
  int tid = threadIdx.x;
  int hw0 = blockIdx.x*512 + tid*2;
  int m0 = blockIdx.y*MT;
  float2 acc[MT];
  #pragma unroll
  for (int i=0;i<MT;i++) acc[i]=make_float2(0.f,0.f);
  {
    float s = 1.f;
    if (gz){ float g = gz[tid]; float g2=g*g; s = g2*g2; }
    zz[tid] = s;
  }
  for (int t0=0;t0<256;t0+=64){
    __syncthreads();
    #pragma unroll
    for (int e=0;e<(64*MT)/256;e++){
      int idx = e*256 + tid;
      int tt = idx >> MTSH, mi = idx & (MT-1);
      As[tt][mi] = A[(size_t)(m0+mi)*256 + t0 + tt] * zz[t0+tt];
    }
    __syncthreads();
    for (int ts=0;ts<64;ts+=8){
      float2 v[8];
      #pragma unroll
      for (int j=0;j<8;j++) v[j] = *(const float2*)(Bv + (size_t)(t0+ts+j)*HW + hw0);
      #pragma unroll
      for (int j=0;j<8;j++){
        const float4* row = (const float4*)&As[ts+j][0];
        #pragma unroll
        for (int q=0;q<MT/4;q++){
          float4 a4 = row[q];
          acc[4*q+0].x += a4.x*v[j].x; acc[4*q+0].y += a4.x*v[j].y;
          acc[4*q+1].x += a4.y*v[j].x; acc[4*q+1].y += a4.y*v[j].y;
          acc[4*q+2].x += a4.z*v[j].x; acc[4*q+2].y += a4.z*v[j].y;
          acc[4*q+3].x += a4.w*v[j].x; acc[4*q+3].y += a4.w*v[j].y;
        }
      }
    }
  }
  #pragma unroll
  for (int mi=0;mi<MT;mi++) *(float2*)(C + (size_t)(m0+mi)*HW + hw0) = acc[mi];
}

// ---------------- Pass 1: fwd 512-pt z-FFT of real tmp, keep kz<=256 -> A[kz][h][wx] ----------
// 16 hw/block (512 threads). Fill only z<256 (upper half handled by HALF_IN); results stored
// straight from registers (res[j] = X[ng+32j]) -> one fewer LDS round-trip + 2 fewer syncs.
__global__ __launch_bounds__(512) void k_fft_zf(const float* __restrict__ tmp,
      float2* __restrict__ A, const float2* __restrict__ tw256, const float2* __restrict__ tw512){
  __shared__ float2 buf[16*LSTR512];    // 66,432 B
  int tid = threadIdx.x;
  int hwl = tid & 15, ng = tid >> 4;
  int hw = blockIdx.x*16 + hwl;
  size_t colbase = (size_t)(hw>>7)*WPAD + (hw & 127);
  float2* ln = buf + hwl*LSTR512;
  #pragma unroll
  for (int a=0;a<8;a++){
    int n = a*32 + ng;
    ln[n] = make_float2(tmp[(size_t)n*HW + hw], 0.f);
  }
  __syncthreads();
  float2 res[8], x256;
  fft512_reg<-1,true>(ln, ng, tw256, tw512, res, x256);
  #pragma unroll
  for (int j=0;j<8;j++){
    int n = ng + 32*j;
    A[(size_t)n*(128*WPAD) + colbase] = res[j];
  }
  if (ng==0) A[(size_t)256*(128*WPAD) + colbase] = x256;
}

// ---------------- Pass 2: fwd y-FFT (128 -> 256) : A[kz][h][wx] -> B[kz][ky][wx] --------------
// Register I/O: global loads feed r[] directly (zero-pad in regs), store B from r[]. 1 sync.
__global__ __launch_bounds__(256) void k_fft_yf(const float2* __restrict__ A,
      float2* __restrict__ B, const float2* __restrict__ tw256){
  __shared__ float2 buf[16*LSTR256];
  int tid = threadIdx.x;
  int w = tid & 15, b = tid >> 4;
  int kz = blockIdx.x;                 // 0..256
  int wx = blockIdx.y*16 + w;          // 0..127
  float2* ln = buf + w*LSTR256;
  size_t abase = (size_t)kz*(128*WPAD) + wx;
  float2 r[16];
  #pragma unroll
  for (int a=0;a<8;a++) r[a] = A[abase + (size_t)(16*a+b)*WPAD];
  #pragma unroll
  for (int a=8;a<16;a++) r[a] = make_float2(0.f,0.f);
  fft256_reg<-1>(r, ln, b, tw256);
  size_t bbase = (size_t)kz*(256*WPAD) + wx;
  #pragma unroll
  for (int a=0;a<16;a++) B[bbase + (size_t)(16*a+b)*WPAD] = r[a];
}

// ---------------- Pass 3: fused x-FFT (zero-pad) + filter (in registers) + inv x-FFT ----------
// Ownership r[a] <-> kx=16a+b matches the FFT's register layout: no LDS fill, no LDS filter,
// no reload. 3 syncs total (vs 9). Table reads scalar (BW-bound; R3/R10 proved shape-neutral).
__global__ __launch_bounds__(256) void k_x_filt(float2* __restrict__ B,
      const float* __restrict__ R, const float* __restrict__ I,
      const float* __restrict__ w0, const float* __restrict__ w1,
      const float2* __restrict__ tw256){
  __shared__ float2 buf[16*LSTR256];
  const float sc = 1.f/33554432.f;     // 1/(512*256*256)
  int tid = threadIdx.x;
  int wl = tid >> 4, b = tid & 15;
  int kz = blockIdx.y;                 // 0..256
  int ky = blockIdx.x*16 + wl;         // 0..255
  float2* ln = buf + wl*LSTR256;
  size_t rb = ((size_t)kz*256 + ky)*WPAD;
  float2 r[16];
  #pragma unroll
  for (int a=0;a<8;a++) r[a] = B[rb + 16*a + b];
  #pragma unroll
  for (int a=8;a<16;a++) r[a] = make_float2(0.f,0.f);
  fft256_reg<-1>(r, ln, b, tw256);
  unsigned mz = (512u - (unsigned)kz) & 511u;
  unsigned my = (256u - (unsigned)ky) & 255u;
  size_t trow = ((size_t)kz<<16) + (size_t)ky*256;
  size_t mrow = ((size_t)mz<<16) + (size_t)my*256;
  #pragma unroll
  for (int a=0;a<16;a++){
    int kx = 16*a + b;
    int mx = (256 - kx) & 255;
    float wr = (R[trow+kx] + 0.5f*(w0[trow+kx] + w0[mrow+mx]))*sc;
    float wi = (I[trow+kx] + 0.5f*(w1[trow+kx] - w1[mrow+mx]))*sc;
    float2 v = r[a];
    r[a] = make_float2(v.x*wr - v.y*wi, v.x*wi + v.y*wr);
  }
  __syncthreads();   // ln reuse: prior transpose-loads must drain before inverse overwrites
  fft256_reg<1>(r, ln, b, tw256);
  #pragma unroll
  for (int a=0;a<8;a++) B[rb + 16*a + b] = r[a];   // keep x<128
}

// ---------------- Pass 4: inv y-FFT, keep y<128 : B[kz][ky][wx] -> A[kz][h][wx] ---------------
__global__ __launch_bounds__(256) void k_fft_yi(const float2* __restrict__ B,
      float2* __restrict__ A, const float2* __restrict__ tw256){
  __shared__ float2 buf[16*LSTR256];
  int tid = threadIdx.x;
  int w = tid & 15, b = tid >> 4;
  int kz = blockIdx.x;                 // 0..256
  int wx = blockIdx.y*16 + w;          // 0..127
  float2* ln = buf + w*LSTR256;
  size_t bbase = (size_t)kz*(256*WPAD) + wx;
  float2 r[16];
  #pragma unroll
  for (int a=0;a<16;a++) r[a] = B[bbase + (size_t)(16*a+b)*WPAD];
  fft256_reg<1>(r, ln, b, tw256);
  size_t abase = (size_t)kz*(128*WPAD) + wx;
  #pragma unroll
  for (int a=0;a<8;a++) A[abase + (size_t)(16*a+b)*WPAD] = r[a];   // keep h<128
}

// ---------------- Pass 5: inv 512-pt z-FFT with Hermitian reconstruction, write real t<256 ----
// 16 hw/block; vol written straight from res[j].x.
__global__ __launch_bounds__(512) void k_fft_zi(const float2* __restrict__ A,
      float* __restrict__ vol, const float2* __restrict__ tw256, const float2* __restrict__ tw512){
  __shared__ float2 buf[16*LSTR512];    // 66,432 B
  int tid = threadIdx.x;
  int hwl = tid & 15, ng = tid >> 4;
  int hw = blockIdx.x*16 + hwl;
  size_t colbase = (size_t)(hw>>7)*WPAD + (hw & 127);
  float2* ln = buf + hwl*LSTR512;
  #pragma unroll
  for (int a=0;a<8;a++){
    int n = a*32 + ng;
    ln[n] = A[(size_t)n*(128*WPAD) + colbase];
  }
  if (ng==0) ln[256] = A[(size_t)256*(128*WPAD) + colbase];
  __syncthreads();
  #pragma unroll
  for (int a=8;a<16;a++){
    int n = a*32 + ng;   // 256..511
    if (n > 256){ float2 v = ln[512-n]; ln[n] = make_float2(v.x, -v.y); }
  }
  __syncthreads();
  float2 res[8], dummy;
  fft512_reg<1,false>(ln, ng, tw256, tw512, res, dummy);
  #pragma unroll
  for (int j=0;j<8;j++){
    int n = ng + 32*j;   // t 0..255
    vol[(size_t)n*HW + hw] = res[j].x;
  }
}

extern "C" void kernel_launch(void* const* d_in, const int* in_sizes, int n_in,
                              void* d_out, int out_size, void* d_ws, size_t ws_size,
                              hipStream_t stream) {
  const float* fet = (const float*)d_in[0];           // (1,1,256,128,128)
  const float* gz  = (const float*)d_in[1];           // (1,256,1,1)
  const float* mtx = (const float*)d_in[2];           // (256,256)
  const float* mtxi= (const float*)d_in[3];           // (256,256)
  const float* Rr  = (const float*)d_in[4];           // (512,256,256)
  const float* Ii  = (const float*)d_in[5];           // (512,256,256)
  const float* lw  = (const float*)d_in[6];           // (2,512,256,256)
  const float* w0  = lw;
  const float* w1  = lw + (size_t)Z2*Y2*X2;
  float* out = (float*)d_out;

  char* ws = (char*)d_ws;
  const size_t OFF_TW256 = 0;
  const size_t OFF_TW512 = 2048;
  const size_t OFF_TMP   = 8192;                                      // tmp / vol (17 MB)
  const size_t TMP_BYTES = (size_t)TC*HW*sizeof(float);
  const size_t OFF_A     = OFF_TMP + TMP_BYTES;
  const size_t A_BYTES   = (size_t)KZS*128*WPAD*sizeof(float2);       // 34.7 MB
  const size_t OFF_B     = OFF_A + A_BYTES;
  const size_t B_BYTES   = (size_t)KZS*256*WPAD*sizeof(float2);       // 69.5 MB
  const size_t NEED      = OFF_B + B_BYTES;                           // ~121 MB
  if (ws_size < NEED) return;   // diagnostic: leaves d_out zero

  float2* tw256 = (float2*)(ws + OFF_TW256);
  float2* tw512 = (float2*)(ws + OFF_TW512);
  float*  tmp   = (float*)(ws + OFF_TMP);   // live: gemm -> zf
  float*  vol   = (float*)(ws + OFF_TMP);   // live: zi -> gemm2
  float2* A     = (float2*)(ws + OFF_A);
  float2* B     = (float2*)(ws + OFF_B);

  hipLaunchKernelGGL(k_init_tw, dim3(1), dim3(512), 0, stream, tw256, tw512);
  hipLaunchKernelGGL(k_gemm, dim3(32,256/MT), dim3(256), 0, stream, mtx, fet, gz, tmp);
  hipLaunchKernelGGL(k_fft_zf, dim3(1024), dim3(512), 0, stream, tmp, A, tw256, tw512);
  hipLaunchKernelGGL(k_fft_yf, dim3(KZS,8), dim3(256), 0, stream, A, B, tw256);
  hipLaunchKernelGGL(k_x_filt, dim3(16,KZS), dim3(256), 0, stream, B, Rr, Ii, w0, w1, tw256);
  hipLaunchKernelGGL(k_fft_yi, dim3(KZS,8), dim3(256), 0, stream, B, A, tw256);
  hipLaunchKernelGGL(k_fft_zi, dim3(1024), dim3(512), 0, stream, A, vol, tw256, tw512);
  hipLaunchKernelGGL(k_gemm, dim3(32,256/MT), dim3(256), 0, stream, mtxi, vol, (const float*)nullptr, out);
}

// Round 13
// 289.090 us; speedup vs baseline: 1.4087x; 1.1694x over previous
//
#include <hip/hip_runtime.h>
#include <math.h>

// Problem constants
#define TC 256            // crop T
#define HC 128            // spatial H=W
#define Z2 512            // 2*T
#define Y2 256            // 2*H
#define X2 256            // 2*W
#define HW 16384          // HC*HC
#define LSTR256 260       // LDS line stride for 256-pt lines (float2)
#define LSTR512 519       // LDS line stride for 512-pt lines (float2)
#define MTSH 4
#define MT (1<<MTSH)      // per-thread m-tile in GEMM (16)
#define WPAD 132          // row stride (float2) for A/B spectral arrays (1056B, non-pow2)
#define KZS 257           // stored z-spectral bins (Hermitian half along z)

__device__ __forceinline__ float2 cadd(float2 a, float2 b){ return make_float2(a.x+b.x, a.y+b.y); }
__device__ __forceinline__ float2 csub(float2 a, float2 b){ return make_float2(a.x-b.x, a.y-b.y); }

// w stored as e^{-2*pi*i*j/N}. SGN=-1 uses w as-is (forward), SGN=+1 uses conj(w) (inverse).
template<int SGN>
__device__ __forceinline__ float2 cmul_tw(float2 z, float2 w){
  float wy = (SGN < 0) ? w.y : -w.y;
  return make_float2(z.x*w.x - z.y*wy, z.x*wy + z.y*w.x);
}
// SGN=-1: multiply by -i ; SGN=+1: multiply by +i
template<int SGN>
__device__ __forceinline__ float2 mul_pmi(float2 t){
  return (SGN < 0) ? make_float2(t.y, -t.x) : make_float2(-t.y, t.x);
}

// In-register 16-point DFT
template<int SGN>
__device__ __forceinline__ void dft16(float2 r[16], const float2* __restrict__ tw){
  float2 u[16];
  #pragma unroll
  for (int b2=0;b2<4;b2++){
    float2 x0=r[b2], x1=r[4+b2], x2=r[8+b2], x3=r[12+b2];
    float2 t0=cadd(x0,x2), t1=csub(x0,x2), t2=cadd(x1,x3), t3=csub(x1,x3);
    float2 y0=cadd(t0,t2), y2=csub(t0,t2);
    float2 t3i = mul_pmi<SGN>(t3);
    float2 y1=cadd(t1,t3i), y3=csub(t1,t3i);
    u[0*4+b2]=y0;
    u[1*4+b2]=cmul_tw<SGN>(y1, tw[(16*b2)&255]);
    u[2*4+b2]=cmul_tw<SGN>(y2, tw[(32*b2)&255]);
    u[3*4+b2]=cmul_tw<SGN>(y3, tw[(48*b2)&255]);
  }
  #pragma unroll
  for (int e2=0;e2<4;e2++){
    float2 x0=u[e2*4+0], x1=u[e2*4+1], x2=u[e2*4+2], x3=u[e2*4+3];
    float2 t0=cadd(x0,x2), t1=csub(x0,x2), t2=cadd(x1,x3), t3=csub(x1,x3);
    float2 t3i = mul_pmi<SGN>(t3);
    r[0*4+e2]=cadd(t0,t2);
    r[1*4+e2]=cadd(t1,t3i);
    r[2*4+e2]=csub(t0,t2);
    r[3*4+e2]=csub(t1,t3i);
  }
}

// Register-I/O 256-pt FFT: input r[a] = element 16a+b, output r[d] = element 16d+b.
// Uses ln (>=256 float2) as transpose scratch. ONE internal sync.
// Caller contract: ln must be safe to overwrite on entry (fresh, or sync'd);
// on return ln holds intermediates (sync before reusing it).
template<int SGN>
__device__ __forceinline__ void fft256_reg(float2 r[16], float2* ln, int b,
                                           const float2* __restrict__ tw){
  dft16<SGN>(r, tw);
  #pragma unroll
  for (int e=1;e<16;e++) r[e] = cmul_tw<SGN>(r[e], tw[(b*e)&255]);
  #pragma unroll
  for (int e=0;e<16;e++) ln[16*e+b] = r[e];
  __syncthreads();
  #pragma unroll
  for (int a=0;a<16;a++) r[a] = ln[16*b+a];
  dft16<SGN>(r, tw);
}

// LDS-based 256-pt FFT on one line (contiguous 256 float2 at ln), 16 threads/line.
// Caller must __syncthreads() after filling ln. Result left in ln (natural order).
template<int SGN>
__device__ __forceinline__ void fft256(float2* ln, int b, const float2* __restrict__ tw){
  float2 r[16];
  #pragma unroll
  for (int a=0;a<16;a++) r[a] = ln[16*a+b];
  dft16<SGN>(r, tw);
  #pragma unroll
  for (int e=1;e<16;e++) r[e] = cmul_tw<SGN>(r[e], tw[(b*e)&255]);
  __syncthreads();
  #pragma unroll
  for (int e=0;e<16;e++) ln[16*e+b] = r[e];
  __syncthreads();
  #pragma unroll
  for (int a=0;a<16;a++) r[a] = ln[16*b+a];
  dft16<SGN>(r, tw);
  __syncthreads();
  #pragma unroll
  for (int d=0;d<16;d++) ln[16*d+b] = r[d];
  __syncthreads();
}

// Register-output 512-pt FFT on an LDS line of 512 float2. 32 threads/line, lt in [0,32).
// Input: ln[0..511] filled (if HALF_IN, only ln[0..255] need be valid; upper half treated 0).
// Output: res[j] = X[lt+32*j] (k=0..255); x256 = X[256] valid on lt==0 threads.
// Caller must __syncthreads() after filling ln. No trailing sync (ln dirty on return).
template<int SGN, bool HALF_IN>
__device__ __forceinline__ void fft512_reg(float2* ln, int lt,
        const float2* __restrict__ tw256, const float2* __restrict__ tw512,
        float2 res[8], float2& x256){
  int team = lt >> 4, b = lt & 15;
  float2* sc = ln + team*256;
  float2 r[16];
  #pragma unroll
  for (int a=0;a<16;a++){
    if (HALF_IN && a>=8) r[a] = make_float2(0.f,0.f);
    else r[a] = ln[2*(16*a+b) + team];
  }
  dft16<SGN>(r, tw256);
  #pragma unroll
  for (int e=1;e<16;e++) r[e] = cmul_tw<SGN>(r[e], tw256[(b*e)&255]);
  __syncthreads();
  #pragma unroll
  for (int e=0;e<16;e++) sc[16*e+b] = r[e];
  __syncthreads();
  #pragma unroll
  for (int a=0;a<16;a++) r[a] = sc[16*b+a];
  dft16<SGN>(r, tw256);
  __syncthreads();
  if (team==0){
    #pragma unroll
    for (int d=0;d<16;d++) ln[16*d+b] = r[d];
  } else {
    #pragma unroll
    for (int d=0;d<16;d++){ int k=16*d+b; ln[256+k] = cmul_tw<SGN>(r[d], tw512[k]); }
  }
  __syncthreads();
  #pragma unroll
  for (int j=0;j<8;j++){
    int k = lt + 32*j;
    float2 E = ln[k], WO = ln[256+k];
    res[j] = cadd(E,WO);
    if (j==0) x256 = csub(E,WO);
  }
}

// ---------------- twiddle init ----------------
__global__ void k_init_tw(float2* tw256, float2* tw512){
  int j = threadIdx.x;  // 512 threads
  if (j < 512){
    double a = -6.283185307179586476925286766559 * (double)j / 512.0;
    tw512[j] = make_float2((float)cos(a), (float)sin(a));
  }
  if (j < 256){
    double a = -6.283185307179586476925286766559 * (double)j / 256.0;
    tw256[j] = make_float2((float)cos(a), (float)sin(a));
  }
}

// ---------------- GEMM: C[m][hw] = sum_t A[m][t]*(gz?gz[t]^4:1) * B[t][hw] ----------------
__global__ __launch_bounds__(256) void k_gemm(const float* __restrict__ A,
    const float* __restrict__ Bv, const float* __restrict__ gz, float* __restrict__ C){
  __shared__ float As[64][MT];   // [tt][mi], scaled by zz[t]
  __shared__ float zz[256];
  int tid = threadIdx.x;
  int hw0 = blockIdx.x*512 + tid*2;
  int m0 = blockIdx.y*MT;
  float2 acc[MT];
  #pragma unroll
  for (int i=0;i<MT;i++) acc[i]=make_float2(0.f,0.f);
  {
    float s = 1.f;
    if (gz){ float g = gz[tid]; float g2=g*g; s = g2*g2; }
    zz[tid] = s;
  }
  for (int t0=0;t0<256;t0+=64){
    __syncthreads();
    #pragma unroll
    for (int e=0;e<(64*MT)/256;e++){
      int idx = e*256 + tid;
      int tt = idx >> MTSH, mi = idx & (MT-1);
      As[tt][mi] = A[(size_t)(m0+mi)*256 + t0 + tt] * zz[t0+tt];
    }
    __syncthreads();
    for (int ts=0;ts<64;ts+=8){
      float2 v[8];
      #pragma unroll
      for (int j=0;j<8;j++) v[j] = *(const float2*)(Bv + (size_t)(t0+ts+j)*HW + hw0);
      #pragma unroll
      for (int j=0;j<8;j++){
        const float4* row = (const float4*)&As[ts+j][0];
        #pragma unroll
        for (int q=0;q<MT/4;q++){
          float4 a4 = row[q];
          acc[4*q+0].x += a4.x*v[j].x; acc[4*q+0].y += a4.x*v[j].y;
          acc[4*q+1].x += a4.y*v[j].x; acc[4*q+1].y += a4.y*v[j].y;
          acc[4*q+2].x += a4.z*v[j].x; acc[4*q+2].y += a4.z*v[j].y;
          acc[4*q+3].x += a4.w*v[j].x; acc[4*q+3].y += a4.w*v[j].y;
        }
      }
    }
  }
  #pragma unroll
  for (int mi=0;mi<MT;mi++) *(float2*)(C + (size_t)(m0+mi)*HW + hw0) = acc[mi];
}

// ---------------- Pass 1: fwd 512-pt z-FFT of real tmp, keep kz<=256 -> A[kz][h][wx] ----------
// 16 hw/block (512 threads). Fill only z<256 (HALF_IN); store straight from registers.
__global__ __launch_bounds__(512) void k_fft_zf(const float* __restrict__ tmp,
      float2* __restrict__ A, const float2* __restrict__ tw256, const float2* __restrict__ tw512){
  __shared__ float2 buf[16*LSTR512];    // 66,432 B
  int tid = threadIdx.x;
  int hwl = tid & 15, ng = tid >> 4;
  int hw = blockIdx.x*16 + hwl;
  size_t colbase = (size_t)(hw>>7)*WPAD + (hw & 127);
  float2* ln = buf + hwl*LSTR512;
  #pragma unroll
  for (int a=0;a<8;a++){
    int n = a*32 + ng;
    ln[n] = make_float2(tmp[(size_t)n*HW + hw], 0.f);
  }
  __syncthreads();
  float2 res[8], x256;
  fft512_reg<-1,true>(ln, ng, tw256, tw512, res, x256);
  #pragma unroll
  for (int j=0;j<8;j++){
    int n = ng + 32*j;
    A[(size_t)n*(128*WPAD) + colbase] = res[j];
  }
  if (ng==0) A[(size_t)256*(128*WPAD) + colbase] = x256;
}

// ---------------- Pass 2: fwd y-FFT (128 -> 256) : A[kz][h][wx] -> B[kz][ky][wx] --------------
// Register I/O: global loads feed r[] directly (zero-pad in regs), store B from r[]. 1 sync.
__global__ __launch_bounds__(256) void k_fft_yf(const float2* __restrict__ A,
      float2* __restrict__ B, const float2* __restrict__ tw256){
  __shared__ float2 buf[16*LSTR256];
  int tid = threadIdx.x;
  int w = tid & 15, b = tid >> 4;
  int kz = blockIdx.x;                 // 0..256
  int wx = blockIdx.y*16 + w;          // 0..127
  float2* ln = buf + w*LSTR256;
  size_t abase = (size_t)kz*(128*WPAD) + wx;
  float2 r[16];
  #pragma unroll
  for (int a=0;a<8;a++) r[a] = A[abase + (size_t)(16*a+b)*WPAD];
  #pragma unroll
  for (int a=8;a<16;a++) r[a] = make_float2(0.f,0.f);
  fft256_reg<-1>(r, ln, b, tw256);
  size_t bbase = (size_t)kz*(256*WPAD) + wx;
  #pragma unroll
  for (int a=0;a<16;a++) B[bbase + (size_t)(16*a+b)*WPAD] = r[a];
}

// ---------------- Pass 3: fused x-FFT (zero-pad 128->256) + filter + inv x-FFT, keep x<128 ----
// LDS-based (R10 version): spectrum stays in LDS during the filter phase so registers are
// free for the table-load latency pipeline (R12's register-resident variant was −80 µs).
// Filter table reads vectorized: thread b owns kx = 64L+4b+j -> forward float4; mirror
// float4 at (252-k0) + scalar at (256-k0)&255 (wrap handles kx=0; no OOB).
__global__ __launch_bounds__(256) void k_x_filt(float2* __restrict__ B,
      const float* __restrict__ R, const float* __restrict__ I,
      const float* __restrict__ w0, const float* __restrict__ w1,
      const float2* __restrict__ tw256){
  __shared__ float2 buf[16*LSTR256];
  const float sc = 1.f/33554432.f;     // 1/(512*256*256)
  int tid = threadIdx.x;
  int wl = tid >> 4, b = tid & 15;
  int kz = blockIdx.y;                 // 0..256
  int ky = blockIdx.x*16 + wl;         // 0..255
  float2* ln = buf + wl*LSTR256;
  size_t rb = ((size_t)kz*256 + ky)*WPAD;
  #pragma unroll
  for (int a=0;a<8;a++){
    int n = 16*a + b;
    ln[n] = B[rb + n];
    ln[n+128] = make_float2(0.f,0.f);
  }
  __syncthreads();
  fft256<-1>(ln, b, tw256);
  unsigned mz = (512u - (unsigned)kz) & 511u;
  unsigned my = (256u - (unsigned)ky) & 255u;
  size_t trow = ((size_t)kz<<16) + (size_t)ky*256;
  size_t mrow = ((size_t)mz<<16) + (size_t)my*256;
  const float* Rrow  = R  + trow;
  const float* Irow  = I  + trow;
  const float* w0row = w0 + trow;
  const float* w1row = w1 + trow;
  const float* w0mr  = w0 + mrow;
  const float* w1mr  = w1 + mrow;
  #pragma unroll
  for (int L=0; L<4; ++L){
    int k0 = L*64 + 4*b;
    float4 Rf  = *(const float4*)(Rrow  + k0);
    float4 If  = *(const float4*)(Irow  + k0);
    float4 w0f = *(const float4*)(w0row + k0);
    float4 w1f = *(const float4*)(w1row + k0);
    float4 q0 = *(const float4*)(w0mr + 252 - k0);   // mx = 252-k0 .. 255-k0
    float4 q1 = *(const float4*)(w1mr + 252 - k0);
    float s0 = w0mr[(256 - k0) & 255];               // mx for j=0 (handles wrap kx=0)
    float s1 = w1mr[(256 - k0) & 255];
    float w0m0=s0, w0m1=q0.w, w0m2=q0.z, w0m3=q0.y;
    float w1m0=s1, w1m1=q1.w, w1m2=q1.z, w1m3=q1.y;
    float wr0=(Rf.x+0.5f*(w0f.x+w0m0))*sc, wi0=(If.x+0.5f*(w1f.x-w1m0))*sc;
    float wr1=(Rf.y+0.5f*(w0f.y+w0m1))*sc, wi1=(If.y+0.5f*(w1f.y-w1m1))*sc;
    float wr2=(Rf.z+0.5f*(w0f.z+w0m2))*sc, wi2=(If.z+0.5f*(w1f.z-w1m2))*sc;
    float wr3=(Rf.w+0.5f*(w0f.w+w0m3))*sc, wi3=(If.w+0.5f*(w1f.w-w1m3))*sc;
    float2 v0=ln[k0], v1=ln[k0+1], v2=ln[k0+2], v3=ln[k0+3];
    ln[k0]   = make_float2(v0.x*wr0 - v0.y*wi0, v0.x*wi0 + v0.y*wr0);
    ln[k0+1] = make_float2(v1.x*wr1 - v1.y*wi1, v1.x*wi1 + v1.y*wr1);
    ln[k0+2] = make_float2(v2.x*wr2 - v2.y*wi2, v2.x*wi2 + v2.y*wr2);
    ln[k0+3] = make_float2(v3.x*wr3 - v3.y*wi3, v3.x*wi3 + v3.y*wr3);
  }
  __syncthreads();   // ownership changed (64L+4b+j), must sync before inverse FFT reads 16a+b
  fft256<1>(ln, b, tw256);
  #pragma unroll
  for (int a=0;a<8;a++){
    int n = 16*a + b;    // x 0..127
    B[rb + n] = ln[n];
  }
}

// ---------------- Pass 4: inv y-FFT, keep y<128 : B[kz][ky][wx] -> A[kz][h][wx] ---------------
__global__ __launch_bounds__(256) void k_fft_yi(const float2* __restrict__ B,
      float2* __restrict__ A, const float2* __restrict__ tw256){
  __shared__ float2 buf[16*LSTR256];
  int tid = threadIdx.x;
  int w = tid & 15, b = tid >> 4;
  int kz = blockIdx.x;                 // 0..256
  int wx = blockIdx.y*16 + w;          // 0..127
  float2* ln = buf + w*LSTR256;
  size_t bbase = (size_t)kz*(256*WPAD) + wx;
  float2 r[16];
  #pragma unroll
  for (int a=0;a<16;a++) r[a] = B[bbase + (size_t)(16*a+b)*WPAD];
  fft256_reg<1>(r, ln, b, tw256);
  size_t abase = (size_t)kz*(128*WPAD) + wx;
  #pragma unroll
  for (int a=0;a<8;a++) A[abase + (size_t)(16*a+b)*WPAD] = r[a];   // keep h<128
}

// ---------------- Pass 5: inv 512-pt z-FFT with Hermitian reconstruction, write real t<256 ----
// 16 hw/block; vol written straight from res[j].x.
__global__ __launch_bounds__(512) void k_fft_zi(const float2* __restrict__ A,
      float* __restrict__ vol, const float2* __restrict__ tw256, const float2* __restrict__ tw512){
  __shared__ float2 buf[16*LSTR512];    // 66,432 B
  int tid = threadIdx.x;
  int hwl = tid & 15, ng = tid >> 4;
  int hw = blockIdx.x*16 + hwl;
  size_t colbase = (size_t)(hw>>7)*WPAD + (hw & 127);
  float2* ln = buf + hwl*LSTR512;
  #pragma unroll
  for (int a=0;a<8;a++){
    int n = a*32 + ng;
    ln[n] = A[(size_t)n*(128*WPAD) + colbase];
  }
  if (ng==0) ln[256] = A[(size_t)256*(128*WPAD) + colbase];
  __syncthreads();
  #pragma unroll
  for (int a=8;a<16;a++){
    int n = a*32 + ng;   // 256..511
    if (n > 256){ float2 v = ln[512-n]; ln[n] = make_float2(v.x, -v.y); }
  }
  __syncthreads();
  float2 res[8], dummy;
  fft512_reg<1,false>(ln, ng, tw256, tw512, res, dummy);
  #pragma unroll
  for (int j=0;j<8;j++){
    int n = ng + 32*j;   // t 0..255
    vol[(size_t)n*HW + hw] = res[j].x;
  }
}

extern "C" void kernel_launch(void* const* d_in, const int* in_sizes, int n_in,
                              void* d_out, int out_size, void* d_ws, size_t ws_size,
                              hipStream_t stream) {
  const float* fet = (const float*)d_in[0];           // (1,1,256,128,128)
  const float* gz  = (const float*)d_in[1];           // (1,256,1,1)
  const float* mtx = (const float*)d_in[2];           // (256,256)
  const float* mtxi= (const float*)d_in[3];           // (256,256)
  const float* Rr  = (const float*)d_in[4];           // (512,256,256)
  const float* Ii  = (const float*)d_in[5];           // (512,256,256)
  const float* lw  = (const float*)d_in[6];           // (2,512,256,256)
  const float* w0  = lw;
  const float* w1  = lw + (size_t)Z2*Y2*X2;
  float* out = (float*)d_out;

  char* ws = (char*)d_ws;
  const size_t OFF_TW256 = 0;
  const size_t OFF_TW512 = 2048;
  const size_t OFF_TMP   = 8192;                                      // tmp / vol (17 MB)
  const size_t TMP_BYTES = (size_t)TC*HW*sizeof(float);
  const size_t OFF_A     = OFF_TMP + TMP_BYTES;
  const size_t A_BYTES   = (size_t)KZS*128*WPAD*sizeof(float2);       // 34.7 MB
  const size_t OFF_B     = OFF_A + A_BYTES;
  const size_t B_BYTES   = (size_t)KZS*256*WPAD*sizeof(float2);       // 69.5 MB
  const size_t NEED      = OFF_B + B_BYTES;                           // ~121 MB
  if (ws_size < NEED) return;   // diagnostic: leaves d_out zero

  float2* tw256 = (float2*)(ws + OFF_TW256);
  float2* tw512 = (float2*)(ws + OFF_TW512);
  float*  tmp   = (float*)(ws + OFF_TMP);   // live: gemm -> zf
  float*  vol   = (float*)(ws + OFF_TMP);   // live: zi -> gemm2
  float2* A     = (float2*)(ws + OFF_A);
  float2* B     = (float2*)(ws + OFF_B);

  hipLaunchKernelGGL(k_init_tw, dim3(1), dim3(512), 0, stream, tw256, tw512);
  hipLaunchKernelGGL(k_gemm, dim3(32,256/MT), dim3(256), 0, stream, mtx, fet, gz, tmp);
  hipLaunchKernelGGL(k_fft_zf, dim3(1024), dim3(512), 0, stream, tmp, A, tw256, tw512);
  hipLaunchKernelGGL(k_fft_yf, dim3(KZS,8), dim3(256), 0, stream, A, B, tw256);
  hipLaunchKernelGGL(k_x_filt, dim3(16,KZS), dim3(256), 0, stream, B, Rr, Ii, w0, w1, tw256);
  hipLaunchKernelGGL(k_fft_yi, dim3(KZS,8), dim3(256), 0, stream, B, A, tw256);
  hipLaunchKernelGGL(k_fft_zi, dim3(1024), dim3(512), 0, stream, A, vol, tw256, tw512);
  hipLaunchKernelGGL(k_gemm, dim3(32,256/MT), dim3(256), 0, stream, mtxi, vol, (const float*)nullptr, out);
}

// Round 14
// 284.403 us; speedup vs baseline: 1.4319x; 1.0165x over previous
//
#include <hip/hip_runtime.h>
#include <math.h>

// Problem constants
#define TC 256            // crop T
#define HC 128            // spatial H=W
#define Z2 512            // 2*T
#define Y2 256            // 2*H
#define X2 256            // 2*W
#define HW 16384          // HC*HC
#define LSTR256 260       // LDS line stride for 256-pt lines (float2)
#define LSTR512 519       // LDS line stride for 512-pt lines (float2)
#define WPAD 132          // row stride (float2) for A/B spectral arrays (1056B, non-pow2)
#define KZS 257           // stored z-spectral bins (Hermitian half along z)

__device__ __forceinline__ float2 cadd(float2 a, float2 b){ return make_float2(a.x+b.x, a.y+b.y); }
__device__ __forceinline__ float2 csub(float2 a, float2 b){ return make_float2(a.x-b.x, a.y-b.y); }

// w stored as e^{-2*pi*i*j/N}. SGN=-1 uses w as-is (forward), SGN=+1 uses conj(w) (inverse).
template<int SGN>
__device__ __forceinline__ float2 cmul_tw(float2 z, float2 w){
  float wy = (SGN < 0) ? w.y : -w.y;
  return make_float2(z.x*w.x - z.y*wy, z.x*wy + z.y*w.x);
}
// SGN=-1: multiply by -i ; SGN=+1: multiply by +i
template<int SGN>
__device__ __forceinline__ float2 mul_pmi(float2 t){
  return (SGN < 0) ? make_float2(t.y, -t.x) : make_float2(-t.y, t.x);
}

// In-register 16-point DFT
template<int SGN>
__device__ __forceinline__ void dft16(float2 r[16], const float2* __restrict__ tw){
  float2 u[16];
  #pragma unroll
  for (int b2=0;b2<4;b2++){
    float2 x0=r[b2], x1=r[4+b2], x2=r[8+b2], x3=r[12+b2];
    float2 t0=cadd(x0,x2), t1=csub(x0,x2), t2=cadd(x1,x3), t3=csub(x1,x3);
    float2 y0=cadd(t0,t2), y2=csub(t0,t2);
    float2 t3i = mul_pmi<SGN>(t3);
    float2 y1=cadd(t1,t3i), y3=csub(t1,t3i);
    u[0*4+b2]=y0;
    u[1*4+b2]=cmul_tw<SGN>(y1, tw[(16*b2)&255]);
    u[2*4+b2]=cmul_tw<SGN>(y2, tw[(32*b2)&255]);
    u[3*4+b2]=cmul_tw<SGN>(y3, tw[(48*b2)&255]);
  }
  #pragma unroll
  for (int e2=0;e2<4;e2++){
    float2 x0=u[e2*4+0], x1=u[e2*4+1], x2=u[e2*4+2], x3=u[e2*4+3];
    float2 t0=cadd(x0,x2), t1=csub(x0,x2), t2=cadd(x1,x3), t3=csub(x1,x3);
    float2 t3i = mul_pmi<SGN>(t3);
    r[0*4+e2]=cadd(t0,t2);
    r[1*4+e2]=cadd(t1,t3i);
    r[2*4+e2]=csub(t0,t2);
    r[3*4+e2]=csub(t1,t3i);
  }
}

// Register-I/O 256-pt FFT: input r[a] = element 16a+b, output r[d] = element 16d+b.
// Uses ln (>=256 float2) as transpose scratch. ONE internal sync.
// Caller contract: ln must be safe to overwrite on entry (fresh, or sync'd);
// on return ln holds intermediates (sync before reusing it).
template<int SGN>
__device__ __forceinline__ void fft256_reg(float2 r[16], float2* ln, int b,
                                           const float2* __restrict__ tw){
  dft16<SGN>(r, tw);
  #pragma unroll
  for (int e=1;e<16;e++) r[e] = cmul_tw<SGN>(r[e], tw[(b*e)&255]);
  #pragma unroll
  for (int e=0;e<16;e++) ln[16*e+b] = r[e];
  __syncthreads();
  #pragma unroll
  for (int a=0;a<16;a++) r[a] = ln[16*b+a];
  dft16<SGN>(r, tw);
}

// LDS-based 256-pt FFT on one line (contiguous 256 float2 at ln), 16 threads/line.
// Caller must __syncthreads() after filling ln. Result left in ln (natural order).
template<int SGN>
__device__ __forceinline__ void fft256(float2* ln, int b, const float2* __restrict__ tw){
  float2 r[16];
  #pragma unroll
  for (int a=0;a<16;a++) r[a] = ln[16*a+b];
  dft16<SGN>(r, tw);
  #pragma unroll
  for (int e=1;e<16;e++) r[e] = cmul_tw<SGN>(r[e], tw[(b*e)&255]);
  __syncthreads();
  #pragma unroll
  for (int e=0;e<16;e++) ln[16*e+b] = r[e];
  __syncthreads();
  #pragma unroll
  for (int a=0;a<16;a++) r[a] = ln[16*b+a];
  dft16<SGN>(r, tw);
  __syncthreads();
  #pragma unroll
  for (int d=0;d<16;d++) ln[16*d+b] = r[d];
  __syncthreads();
}

// Register-output 512-pt FFT on an LDS line of 512 float2. 32 threads/line, lt in [0,32).
// Input: ln[0..511] filled (if HALF_IN, only ln[0..255] need be valid; upper half treated 0).
// Output: res[j] = X[lt+32*j] (k=0..255); x256 = X[256] valid on lt==0 threads.
// Caller must __syncthreads() after filling ln. No trailing sync (ln dirty on return).
template<int SGN, bool HALF_IN>
__device__ __forceinline__ void fft512_reg(float2* ln, int lt,
        const float2* __restrict__ tw256, const float2* __restrict__ tw512,
        float2 res[8], float2& x256){
  int team = lt >> 4, b = lt & 15;
  float2* sc = ln + team*256;
  float2 r[16];
  #pragma unroll
  for (int a=0;a<16;a++){
    if (HALF_IN && a>=8) r[a] = make_float2(0.f,0.f);
    else r[a] = ln[2*(16*a+b) + team];
  }
  dft16<SGN>(r, tw256);
  #pragma unroll
  for (int e=1;e<16;e++) r[e] = cmul_tw<SGN>(r[e], tw256[(b*e)&255]);
  __syncthreads();
  #pragma unroll
  for (int e=0;e<16;e++) sc[16*e+b] = r[e];
  __syncthreads();
  #pragma unroll
  for (int a=0;a<16;a++) r[a] = sc[16*b+a];
  dft16<SGN>(r, tw256);
  __syncthreads();
  if (team==0){
    #pragma unroll
    for (int d=0;d<16;d++) ln[16*d+b] = r[d];
  } else {
    #pragma unroll
    for (int d=0;d<16;d++){ int k=16*d+b; ln[256+k] = cmul_tw<SGN>(r[d], tw512[k]); }
  }
  __syncthreads();
  #pragma unroll
  for (int j=0;j<8;j++){
    int k = lt + 32*j;
    float2 E = ln[k], WO = ln[256+k];
    res[j] = cadd(E,WO);
    if (j==0) x256 = csub(E,WO);
  }
}

// ---------------- twiddle init ----------------
__global__ void k_init_tw(float2* tw256, float2* tw512){
  int j = threadIdx.x;  // 512 threads
  if (j < 512){
    double a = -6.283185307179586476925286766559 * (double)j / 512.0;
    tw512[j] = make_float2((float)cos(a), (float)sin(a));
  }
  if (j < 256){
    double a = -6.283185307179586476925286766559 * (double)j / 256.0;
    tw256[j] = make_float2((float)cos(a), (float)sin(a));
  }
}

// ---------------- GEMM: C[m][hw] = sum_t A[m][t]*(gz?gz[t]^4:1) * B[t][hw] ----------------
// HWT=4 hw per thread (float4 B loads/stores) -> LDS As traffic 1 B/FMA (was 2 with HWT=2,
// which made the GEMM LDS-BW-bound at ~30 us). MT=8 keeps acc small: ~90 VGPR, no spill.
// Grid (HW/1024, 256/8) = (16,32) = 512 blocks = 2/CU. As reads are wave-broadcast.
__global__ __launch_bounds__(256) void k_gemm(const float* __restrict__ A,
    const float* __restrict__ Bv, const float* __restrict__ gz, float* __restrict__ C){
  __shared__ float As[64][8];    // [tt][mi], scaled by zz[t]
  __shared__ float zz[256];
  int tid = threadIdx.x;
  int hw0 = blockIdx.x*1024 + tid*4;
  int m0 = blockIdx.y*8;
  float4 acc[8];
  #pragma unroll
  for (int i=0;i<8;i++) acc[i]=make_float4(0.f,0.f,0.f,0.f);
  {
    float s = 1.f;
    if (gz){ float g = gz[tid]; float g2=g*g; s = g2*g2; }
    zz[tid] = s;
  }
  for (int t0=0;t0<256;t0+=64){
    __syncthreads();
    #pragma unroll
    for (int e=0;e<2;e++){
      int idx = e*256 + tid;
      int tt = idx >> 3, mi = idx & 7;
      As[tt][mi] = A[(size_t)(m0+mi)*256 + t0 + tt] * zz[t0+tt];
    }
    __syncthreads();
    for (int ts=0;ts<64;ts+=8){
      float4 v[8];
      #pragma unroll
      for (int j=0;j<8;j++) v[j] = *(const float4*)(Bv + (size_t)(t0+ts+j)*HW + hw0);
      #pragma unroll
      for (int j=0;j<8;j++){
        const float4* row = (const float4*)&As[ts+j][0];
        float4 alo = row[0], ahi = row[1];
        acc[0].x += alo.x*v[j].x; acc[0].y += alo.x*v[j].y; acc[0].z += alo.x*v[j].z; acc[0].w += alo.x*v[j].w;
        acc[1].x += alo.y*v[j].x; acc[1].y += alo.y*v[j].y; acc[1].z += alo.y*v[j].z; acc[1].w += alo.y*v[j].w;
        acc[2].x += alo.z*v[j].x; acc[2].y += alo.z*v[j].y; acc[2].z += alo.z*v[j].z; acc[2].w += alo.z*v[j].w;
        acc[3].x += alo.w*v[j].x; acc[3].y += alo.w*v[j].y; acc[3].z += alo.w*v[j].z; acc[3].w += alo.w*v[j].w;
        acc[4].x += ahi.x*v[j].x; acc[4].y += ahi.x*v[j].y; acc[4].z += ahi.x*v[j].z; acc[4].w += ahi.x*v[j].w;
        acc[5].x += ahi.y*v[j].x; acc[5].y += ahi.y*v[j].y; acc[5].z += ahi.y*v[j].z; acc[5].w += ahi.y*v[j].w;
        acc[6].x += ahi.z*v[j].x; acc[6].y += ahi.z*v[j].y; acc[6].z += ahi.z*v[j].z; acc[6].w += ahi.z*v[j].w;
        acc[7].x += ahi.w*v[j].x; acc[7].y += ahi.w*v[j].y; acc[7].z += ahi.w*v[j].z; acc[7].w += ahi.w*v[j].w;
      }
    }
  }
  #pragma unroll
  for (int mi=0;mi<8;mi++) *(float4*)(C + (size_t)(m0+mi)*HW + hw0) = acc[mi];
}

// ---------------- Pass 1: fwd 512-pt z-FFT of real tmp, keep kz<=256 -> A[kz][h][wx] ----------
// 16 hw/block (512 threads). Fill only z<256 (HALF_IN); store straight from registers.
__global__ __launch_bounds__(512) void k_fft_zf(const float* __restrict__ tmp,
      float2* __restrict__ A, const float2* __restrict__ tw256, const float2* __restrict__ tw512){
  __shared__ float2 buf[16*LSTR512];    // 66,432 B
  int tid = threadIdx.x;
  int hwl = tid & 15, ng = tid >> 4;
  int hw = blockIdx.x*16 + hwl;
  size_t colbase = (size_t)(hw>>7)*WPAD + (hw & 127);
  float2* ln = buf + hwl*LSTR512;
  #pragma unroll
  for (int a=0;a<8;a++){
    int n = a*32 + ng;
    ln[n] = make_float2(tmp[(size_t)n*HW + hw], 0.f);
  }
  __syncthreads();
  float2 res[8], x256;
  fft512_reg<-1,true>(ln, ng, tw256, tw512, res, x256);
  #pragma unroll
  for (int j=0;j<8;j++){
    int n = ng + 32*j;
    A[(size_t)n*(128*WPAD) + colbase] = res[j];
  }
  if (ng==0) A[(size_t)256*(128*WPAD) + colbase] = x256;
}

// ---------------- Pass 2: fwd y-FFT (128 -> 256) : A[kz][h][wx] -> B[kz][ky][wx] --------------
// Register I/O: global loads feed r[] directly (zero-pad in regs), store B from r[]. 1 sync.
__global__ __launch_bounds__(256) void k_fft_yf(const float2* __restrict__ A,
      float2* __restrict__ B, const float2* __restrict__ tw256){
  __shared__ float2 buf[16*LSTR256];
  int tid = threadIdx.x;
  int w = tid & 15, b = tid >> 4;
  int kz = blockIdx.x;                 // 0..256
  int wx = blockIdx.y*16 + w;          // 0..127
  float2* ln = buf + w*LSTR256;
  size_t abase = (size_t)kz*(128*WPAD) + wx;
  float2 r[16];
  #pragma unroll
  for (int a=0;a<8;a++) r[a] = A[abase + (size_t)(16*a+b)*WPAD];
  #pragma unroll
  for (int a=8;a<16;a++) r[a] = make_float2(0.f,0.f);
  fft256_reg<-1>(r, ln, b, tw256);
  size_t bbase = (size_t)kz*(256*WPAD) + wx;
  #pragma unroll
  for (int a=0;a<16;a++) B[bbase + (size_t)(16*a+b)*WPAD] = r[a];
}

// ---------------- Pass 3: fused x-FFT (zero-pad 128->256) + filter + inv x-FFT, keep x<128 ----
// LDS-based: spectrum stays in LDS during the filter phase so registers are free for the
// table-load latency pipeline (R12's register-resident variant was -80 us).
// Filter table reads vectorized: thread b owns kx = 64L+4b+j -> forward float4; mirror
// float4 at (252-k0) + scalar at (256-k0)&255 (wrap handles kx=0; no OOB).
__global__ __launch_bounds__(256) void k_x_filt(float2* __restrict__ B,
      const float* __restrict__ R, const float* __restrict__ I,
      const float* __restrict__ w0, const float* __restrict__ w1,
      const float2* __restrict__ tw256){
  __shared__ float2 buf[16*LSTR256];
  const float sc = 1.f/33554432.f;     // 1/(512*256*256)
  int tid = threadIdx.x;
  int wl = tid >> 4, b = tid & 15;
  int kz = blockIdx.y;                 // 0..256
  int ky = blockIdx.x*16 + wl;         // 0..255
  float2* ln = buf + wl*LSTR256;
  size_t rb = ((size_t)kz*256 + ky)*WPAD;
  #pragma unroll
  for (int a=0;a<8;a++){
    int n = 16*a + b;
    ln[n] = B[rb + n];
    ln[n+128] = make_float2(0.f,0.f);
  }
  __syncthreads();
  fft256<-1>(ln, b, tw256);
  unsigned mz = (512u - (unsigned)kz) & 511u;
  unsigned my = (256u - (unsigned)ky) & 255u;
  size_t trow = ((size_t)kz<<16) + (size_t)ky*256;
  size_t mrow = ((size_t)mz<<16) + (size_t)my*256;
  const float* Rrow  = R  + trow;
  const float* Irow  = I  + trow;
  const float* w0row = w0 + trow;
  const float* w1row = w1 + trow;
  const float* w0mr  = w0 + mrow;
  const float* w1mr  = w1 + mrow;
  #pragma unroll
  for (int L=0; L<4; ++L){
    int k0 = L*64 + 4*b;
    float4 Rf  = *(const float4*)(Rrow  + k0);
    float4 If  = *(const float4*)(Irow  + k0);
    float4 w0f = *(const float4*)(w0row + k0);
    float4 w1f = *(const float4*)(w1row + k0);
    float4 q0 = *(const float4*)(w0mr + 252 - k0);   // mx = 252-k0 .. 255-k0
    float4 q1 = *(const float4*)(w1mr + 252 - k0);
    float s0 = w0mr[(256 - k0) & 255];               // mx for j=0 (handles wrap kx=0)
    float s1 = w1mr[(256 - k0) & 255];
    float w0m0=s0, w0m1=q0.w, w0m2=q0.z, w0m3=q0.y;
    float w1m0=s1, w1m1=q1.w, w1m2=q1.z, w1m3=q1.y;
    float wr0=(Rf.x+0.5f*(w0f.x+w0m0))*sc, wi0=(If.x+0.5f*(w1f.x-w1m0))*sc;
    float wr1=(Rf.y+0.5f*(w0f.y+w0m1))*sc, wi1=(If.y+0.5f*(w1f.y-w1m1))*sc;
    float wr2=(Rf.z+0.5f*(w0f.z+w0m2))*sc, wi2=(If.z+0.5f*(w1f.z-w1m2))*sc;
    float wr3=(Rf.w+0.5f*(w0f.w+w0m3))*sc, wi3=(If.w+0.5f*(w1f.w-w1m3))*sc;
    float2 v0=ln[k0], v1=ln[k0+1], v2=ln[k0+2], v3=ln[k0+3];
    ln[k0]   = make_float2(v0.x*wr0 - v0.y*wi0, v0.x*wi0 + v0.y*wr0);
    ln[k0+1] = make_float2(v1.x*wr1 - v1.y*wi1, v1.x*wi1 + v1.y*wr1);
    ln[k0+2] = make_float2(v2.x*wr2 - v2.y*wi2, v2.x*wi2 + v2.y*wr2);
    ln[k0+3] = make_float2(v3.x*wr3 - v3.y*wi3, v3.x*wi3 + v3.y*wr3);
  }
  __syncthreads();   // ownership changed (64L+4b+j), must sync before inverse FFT reads 16a+b
  fft256<1>(ln, b, tw256);
  #pragma unroll
  for (int a=0;a<8;a++){
    int n = 16*a + b;    // x 0..127
    B[rb + n] = ln[n];
  }
}

// ---------------- Pass 4: inv y-FFT, keep y<128 : B[kz][ky][wx] -> A[kz][h][wx] ---------------
__global__ __launch_bounds__(256) void k_fft_yi(const float2* __restrict__ B,
      float2* __restrict__ A, const float2* __restrict__ tw256){
  __shared__ float2 buf[16*LSTR256];
  int tid = threadIdx.x;
  int w = tid & 15, b = tid >> 4;
  int kz = blockIdx.x;                 // 0..256
  int wx = blockIdx.y*16 + w;          // 0..127
  float2* ln = buf + w*LSTR256;
  size_t bbase = (size_t)kz*(256*WPAD) + wx;
  float2 r[16];
  #pragma unroll
  for (int a=0;a<16;a++) r[a] = B[bbase + (size_t)(16*a+b)*WPAD];
  fft256_reg<1>(r, ln, b, tw256);
  size_t abase = (size_t)kz*(128*WPAD) + wx;
  #pragma unroll
  for (int a=0;a<8;a++) A[abase + (size_t)(16*a+b)*WPAD] = r[a];   // keep h<128
}

// ---------------- Pass 5: inv 512-pt z-FFT with Hermitian reconstruction, write real t<256 ----
// 16 hw/block; vol written straight from res[j].x.
__global__ __launch_bounds__(512) void k_fft_zi(const float2* __restrict__ A,
      float* __restrict__ vol, const float2* __restrict__ tw256, const float2* __restrict__ tw512){
  __shared__ float2 buf[16*LSTR512];    // 66,432 B
  int tid = threadIdx.x;
  int hwl = tid & 15, ng = tid >> 4;
  int hw = blockIdx.x*16 + hwl;
  size_t colbase = (size_t)(hw>>7)*WPAD + (hw & 127);
  float2* ln = buf + hwl*LSTR512;
  #pragma unroll
  for (int a=0;a<8;a++){
    int n = a*32 + ng;
    ln[n] = A[(size_t)n*(128*WPAD) + colbase];
  }
  if (ng==0) ln[256] = A[(size_t)256*(128*WPAD) + colbase];
  __syncthreads();
  #pragma unroll
  for (int a=8;a<16;a++){
    int n = a*32 + ng;   // 256..511
    if (n > 256){ float2 v = ln[512-n]; ln[n] = make_float2(v.x, -v.y); }
  }
  __syncthreads();
  float2 res[8], dummy;
  fft512_reg<1,false>(ln, ng, tw256, tw512, res, dummy);
  #pragma unroll
  for (int j=0;j<8;j++){
    int n = ng + 32*j;   // t 0..255
    vol[(size_t)n*HW + hw] = res[j].x;
  }
}

extern "C" void kernel_launch(void* const* d_in, const int* in_sizes, int n_in,
                              void* d_out, int out_size, void* d_ws, size_t ws_size,
                              hipStream_t stream) {
  const float* fet = (const float*)d_in[0];           // (1,1,256,128,128)
  const float* gz  = (const float*)d_in[1];           // (1,256,1,1)
  const float* mtx = (const float*)d_in[2];           // (256,256)
  const float* mtxi= (const float*)d_in[3];           // (256,256)
  const float* Rr  = (const float*)d_in[4];           // (512,256,256)
  const float* Ii  = (const float*)d_in[5];           // (512,256,256)
  const float* lw  = (const float*)d_in[6];           // (2,512,256,256)
  const float* w0  = lw;
  const float* w1  = lw + (size_t)Z2*Y2*X2;
  float* out = (float*)d_out;

  char* ws = (char*)d_ws;
  const size_t OFF_TW256 = 0;
  const size_t OFF_TW512 = 2048;
  const size_t OFF_TMP   = 8192;                                      // tmp / vol (17 MB)
  const size_t TMP_BYTES = (size_t)TC*HW*sizeof(float);
  const size_t OFF_A     = OFF_TMP + TMP_BYTES;
  const size_t A_BYTES   = (size_t)KZS*128*WPAD*sizeof(float2);       // 34.7 MB
  const size_t OFF_B     = OFF_A + A_BYTES;
  const size_t B_BYTES   = (size_t)KZS*256*WPAD*sizeof(float2);       // 69.5 MB
  const size_t NEED      = OFF_B + B_BYTES;                           // ~121 MB
  if (ws_size < NEED) return;   // diagnostic: leaves d_out zero

  float2* tw256 = (float2*)(ws + OFF_TW256);
  float2* tw512 = (float2*)(ws + OFF_TW512);
  float*  tmp   = (float*)(ws + OFF_TMP);   // live: gemm -> zf
  float*  vol   = (float*)(ws + OFF_TMP);   // live: zi -> gemm2
  float2* A     = (float2*)(ws + OFF_A);
  float2* B     = (float2*)(ws + OFF_B);

  hipLaunchKernelGGL(k_init_tw, dim3(1), dim3(512), 0, stream, tw256, tw512);
  hipLaunchKernelGGL(k_gemm, dim3(16,32), dim3(256), 0, stream, mtx, fet, gz, tmp);
  hipLaunchKernelGGL(k_fft_zf, dim3(1024), dim3(512), 0, stream, tmp, A, tw256, tw512);
  hipLaunchKernelGGL(k_fft_yf, dim3(KZS,8), dim3(256), 0, stream, A, B, tw256);
  hipLaunchKernelGGL(k_x_filt, dim3(16,KZS), dim3(256), 0, stream, B, Rr, Ii, w0, w1, tw256);
  hipLaunchKernelGGL(k_fft_yi, dim3(KZS,8), dim3(256), 0, stream, B, A, tw256);
  hipLaunchKernelGGL(k_fft_zi, dim3(1024), dim3(512), 0, stream, A, vol, tw256, tw512);
  hipLaunchKernelGGL(k_gemm, dim3(16,32), dim3(256), 0, stream, mtxi, vol, (const float*)nullptr, out);
}